// Round 2
// baseline (318.385 us; speedup 1.0000x reference)
//
#include <hip/hip_runtime.h>
#include <math.h>

// Problem constants
#define T_DIM 8192
#define N_DIM 4096
#define L 64
#define P 32
#define IN_DIM 192
#define S_CHUNK 32            // states per chunk in k_states
#define N_CHUNK (T_DIM / S_CHUNK)   // 256
#define LDSTRIDE 66           // padded LDS row stride for 64x64 matrices

// ---------------- kernel A: partial sums for xh0 = U^T x0 ----------------
__global__ __launch_bounds__(64) void k_xh0_part(const float* __restrict__ U,
                                                 const float* __restrict__ Xtr,
                                                 float* __restrict__ part) {
  int b = blockIdx.x;      // 64 blocks, each covers 64 rows of U
  int l = threadIdx.x;     // 64 threads = columns
  int n0 = b * 64;
  float acc = 0.f;
  #pragma unroll 8
  for (int i = 0; i < 64; ++i) {
    float x = Xtr[n0 + i];                       // row 0 of X_train (broadcast)
    acc += U[(size_t)(n0 + i) * L + l] * x;      // coalesced across l
  }
  part[b * 64 + l] = acc;
}

// ---------------- kernel B: argmax, temp, build M, xh0, matrix doublings ----------------
__global__ __launch_bounds__(256) void k_prep(const float* __restrict__ A_tilde,
                                              const float* __restrict__ phi_bar_t,
                                              const float* __restrict__ logits,
                                              const float* __restrict__ temp,
                                              const float* __restrict__ part,
                                              float* __restrict__ Wm,    // 13 * 4096 floats (W_0..W_12)
                                              float* __restrict__ xh0,
                                              float* __restrict__ out_tail) { // d_out + T*N
  __shared__ float buf[2][64 * LDSTRIDE];
  __shared__ int sel_s[P];
  int tid = threadIdx.x;

  // argmax per row of logits (first max, matches jnp.argmax)
  if (tid < P) {
    const float* row = logits + tid * IN_DIM;
    float best = row[0]; int bi = 0;
    for (int k = 1; k < IN_DIM; ++k) { float v = row[k]; if (v > best) { best = v; bi = k; } }
    sel_s[tid] = bi;
    out_tail[2 + tid] = (float)bi;      // selected_idx as float
  }
  if (tid == 0) out_tail[1] = fmaxf(0.01f, temp[0] * 0.999f);  // new_temp

  // load A_tilde into buf[0] (padded)
  for (int i = tid; i < L * L; i += 256)
    buf[0][(i >> 6) * LDSTRIDE + (i & 63)] = A_tilde[i];
  __syncthreads();

  // scatter phi: M[l][clip(sel[p])] += phi_bar_t[p][l]; rows owned per-thread (no races)
  if (tid < L) {
    for (int p = 0; p < P; ++p) {
      int kk = sel_s[p]; if (kk > L - 1) kk = L - 1;
      buf[0][tid * LDSTRIDE + kk] += phi_bar_t[p * L + tid];
    }
  }
  // xh0 reduce (different threads, no conflict with scatter)
  if (tid >= 64 && tid < 128) {
    int l = tid - 64; float s = 0.f;
    for (int b = 0; b < 64; ++b) s += part[b * 64 + l];
    xh0[l] = s;
  }
  __syncthreads();

  // write W_0 = M to global
  for (int i = tid; i < L * L; i += 256)
    Wm[i] = buf[0][(i >> 6) * LDSTRIDE + (i & 63)];

  // 12 sequential squarings: W_j = W_{j-1}^2
  int r = tid & 63, cg = tid >> 6;
  int c0 = cg * 16;
  int cur = 0;
  for (int j = 1; j <= 12; ++j) {
    const float* S = buf[cur];
    float* D = buf[cur ^ 1];
    float ar[64];
    #pragma unroll
    for (int k = 0; k < 64; ++k) ar[k] = S[r * LDSTRIDE + k];   // 2-way bank = free
    float acc[16];
    #pragma unroll
    for (int c = 0; c < 16; ++c) acc[c] = 0.f;
    #pragma unroll 4
    for (int k = 0; k < 64; ++k) {
      const float2* bp = (const float2*)(S + k * LDSTRIDE + c0); // broadcast reads
      #pragma unroll
      for (int c2 = 0; c2 < 8; ++c2) {
        float2 b2 = bp[c2];
        acc[2 * c2]     += ar[k] * b2.x;
        acc[2 * c2 + 1] += ar[k] * b2.y;
      }
    }
    #pragma unroll
    for (int c = 0; c < 16; ++c) D[r * LDSTRIDE + c0 + c] = acc[c];
    float* Wout = Wm + j * 4096;
    #pragma unroll
    for (int c = 0; c < 16; ++c) Wout[r * 64 + c0 + c] = acc[c];
    __syncthreads();
    cur ^= 1;
  }
}

// ---------------- kernel C: all 8192 states via checkpoints + serial steps ----------------
__global__ __launch_bounds__(64) void k_states(const float* __restrict__ Wm,
                                               const float* __restrict__ xh0,
                                               float* __restrict__ xseq) {
  int c = blockIdx.x;       // 256 chunks
  int l = threadIdx.x;      // 64 lanes; lane l owns component l
  float v = xh0[l];
  int e = c << 5;           // starting exponent = 32*c (bits 5..12)
  for (int j = 5; j <= 12; ++j) {
    if ((e >> j) & 1) {
      const float* W = Wm + j * 4096;
      float n0 = 0.f, n1 = 0.f, n2 = 0.f, n3 = 0.f;
      #pragma unroll
      for (int k = 0; k < 64; k += 4) {
        n0 += W[l * 64 + k]     * __shfl(v, k, 64);
        n1 += W[l * 64 + k + 1] * __shfl(v, k + 1, 64);
        n2 += W[l * 64 + k + 2] * __shfl(v, k + 2, 64);
        n3 += W[l * 64 + k + 3] * __shfl(v, k + 3, 64);
      }
      v = (n0 + n1) + (n2 + n3);
    }
  }
  // M row l into registers
  float m[64];
  #pragma unroll
  for (int k = 0; k < 64; ++k) m[k] = Wm[l * 64 + k];
  float* out = xseq + (size_t)(c * S_CHUNK) * L;
  for (int i = 0; i < S_CHUNK; ++i) {
    float n0 = 0.f, n1 = 0.f, n2 = 0.f, n3 = 0.f;
    #pragma unroll
    for (int k = 0; k < 64; k += 4) {
      n0 += m[k]     * __shfl(v, k, 64);
      n1 += m[k + 1] * __shfl(v, k + 1, 64);
      n2 += m[k + 2] * __shfl(v, k + 2, 64);
      n3 += m[k + 3] * __shfl(v, k + 3, 64);
    }
    v = (n0 + n1) + (n2 + n3);
    out[i * L + l] = v;      // xh_seq[32c+i] = M^{32c+i+1} xh0
  }
}

// ---------------- kernel D: X_rec = xh_seq @ U^T, fused err partials ----------------
// Block: 256 threads, tile = 64 t x 256 n. xseq tile staged in LDS (16 KiB,
// broadcast reads); each thread keeps its 64-float U row in VGPRs.
// __launch_bounds__(256, 4) caps VGPRs at 128 so the compiler has no pressure
// reason to sink the u[] loads into the t-loop (round-1 failure mode: VGPR=60,
// U re-fetched 64x -> ~8 GiB L2 traffic -> 172 us).
__global__ __launch_bounds__(256, 4) void k_xrec(const float* __restrict__ xseq,
                                                 const float* __restrict__ U,
                                                 const float* __restrict__ Y,
                                                 float* __restrict__ Xrec,
                                                 double* __restrict__ acc) {
  __shared__ float xs[64 * 64];    // 16 KiB: 64 t-rows of 64 floats
  int nt = blockIdx.x & 15;        // 16 n-tiles of 256
  int tt = blockIdx.x >> 4;        // 128 t-tiles of 64
  int tid = threadIdx.x;
  int n = nt * 256 + tid;
  int t0 = tt * 64;

  // stage xseq tile: 4096 floats = 1024 float4, 4 per thread (coalesced)
  {
    const float4* src = (const float4*)(xseq + (size_t)t0 * L);
    float4* dst = (float4*)xs;
    #pragma unroll
    for (int i = 0; i < 4; ++i)
      dst[tid + 256 * i] = src[tid + 256 * i];
  }

  // U row for this thread's n -> registers (64 VGPRs)
  float u[64];
  {
    const float4* Uv = (const float4*)(U + (size_t)n * L);
    #pragma unroll
    for (int i = 0; i < 16; ++i) {
      float4 q = Uv[i];
      u[4 * i] = q.x; u[4 * i + 1] = q.y; u[4 * i + 2] = q.z; u[4 * i + 3] = q.w;
    }
  }
  __syncthreads();

  float sd = 0.f, sy = 0.f;
  #pragma unroll 2
  for (int t = 0; t < 64; ++t) {
    const float4* xr = (const float4*)(xs + t * L);  // wave-uniform -> LDS broadcast
    float a0 = 0.f, a1 = 0.f, a2 = 0.f, a3 = 0.f;
    #pragma unroll
    for (int k = 0; k < 16; ++k) {
      float4 xv = xr[k];
      a0 += xv.x * u[4 * k];
      a1 += xv.y * u[4 * k + 1];
      a2 += xv.z * u[4 * k + 2];
      a3 += xv.w * u[4 * k + 3];
    }
    float x = (a0 + a1) + (a2 + a3);
    size_t idx = (size_t)(t0 + t) * N_DIM + n;
    float y = Y[idx];
    float d = y - x;
    sd += d * d;
    sy += y * y;
    Xrec[idx] = x;
  }

  __shared__ float rs[256], ry[256];
  rs[tid] = sd; ry[tid] = sy;
  __syncthreads();
  for (int s = 128; s > 0; s >>= 1) {
    if (tid < s) { rs[tid] += rs[tid + s]; ry[tid] += ry[tid + s]; }
    __syncthreads();
  }
  if (tid == 0) {
    atomicAdd(acc,     (double)rs[0]);
    atomicAdd(acc + 1, (double)ry[0]);
  }
}

// ---------------- kernel E: finalize err ----------------
__global__ void k_err(const double* __restrict__ acc, float* __restrict__ out_tail) {
  out_tail[0] = (float)sqrt(acc[0] / acc[1]);
}

extern "C" void kernel_launch(void* const* d_in, const int* in_sizes, int n_in,
                              void* d_out, int out_size, void* d_ws, size_t ws_size,
                              hipStream_t stream) {
  const float* X_train = (const float*)d_in[1];   // (T, N), row 0 = x0
  const float* Y       = (const float*)d_in[2];   // (T, N)
  const float* temp    = (const float*)d_in[3];
  const float* phi     = (const float*)d_in[4];   // (P, L)
  const float* A_tilde = (const float*)d_in[5];   // (L, L)
  const float* U       = (const float*)d_in[6];   // (N, L)
  const float* logits  = (const float*)d_in[7];   // (P, IN_DIM)
  float* out = (float*)d_out;
  float* out_tail = out + (size_t)T_DIM * N_DIM;  // [err, new_temp, sel[32]]

  // workspace layout (bytes)
  char* w = (char*)d_ws;
  double* acc  = (double*)w;                       // 2 doubles
  float* Wm    = (float*)(w + 64);                 // 13 * 4096 floats
  float* xh0   = (float*)(w + 64 + 13 * 16384);    // 64 floats
  float* part  = (float*)(w + 213312);             // 64*64 floats
  float* xseq  = (float*)(w + 262144);             // 8192*64 floats (2 MiB)

  hipMemsetAsync(acc, 0, 2 * sizeof(double), stream);

  k_xh0_part<<<64, 64, 0, stream>>>(U, X_train, part);
  k_prep<<<1, 256, 0, stream>>>(A_tilde, phi, logits, temp, part, Wm, xh0, out_tail);
  k_states<<<N_CHUNK, 64, 0, stream>>>(Wm, xh0, xseq);
  k_xrec<<<2048, 256, 0, stream>>>(xseq, U, Y, out, acc);
  k_err<<<1, 1, 0, stream>>>(acc, out_tail);
}

// Round 3
// 186.985 us; speedup vs baseline: 1.7027x; 1.7027x over previous
//
#include <hip/hip_runtime.h>
#include <math.h>

// Problem constants
#define T_DIM 8192
#define N_DIM 4096
#define L 64
#define P 32
#define IN_DIM 192
#define S_CHUNK 16                  // states per chunk in k_states
#define N_CHUNK (T_DIM / S_CHUNK)   // 512
#define LDSTRIDE 66                 // padded LDS row stride for 64x64 matrices

// ---------------- kernel A: partial sums for xh0 = U^T x0 ----------------
__global__ __launch_bounds__(64) void k_xh0_part(const float* __restrict__ U,
                                                 const float* __restrict__ Xtr,
                                                 float* __restrict__ part) {
  int b = blockIdx.x;      // 64 blocks, each covers 64 rows of U
  int l = threadIdx.x;     // 64 threads = columns
  int n0 = b * 64;
  float acc = 0.f;
  #pragma unroll 8
  for (int i = 0; i < 64; ++i) {
    float x = Xtr[n0 + i];                       // row 0 of X_train (broadcast)
    acc += U[(size_t)(n0 + i) * L + l] * x;      // coalesced across l
  }
  part[b * 64 + l] = acc;
}

// ---------------- kernel B: argmax, temp, build M, xh0, matrix doublings ----------------
__global__ __launch_bounds__(256) void k_prep(const float* __restrict__ A_tilde,
                                              const float* __restrict__ phi_bar_t,
                                              const float* __restrict__ logits,
                                              const float* __restrict__ temp,
                                              const float* __restrict__ part,
                                              float* __restrict__ Wm,    // 13 * 4096 floats (W_0..W_12)
                                              float* __restrict__ xh0,
                                              float* __restrict__ out_tail) { // d_out + T*N
  __shared__ float buf[2][64 * LDSTRIDE];
  __shared__ int sel_s[P];
  int tid = threadIdx.x;

  // argmax per row of logits (first max, matches jnp.argmax)
  if (tid < P) {
    const float* row = logits + tid * IN_DIM;
    float best = row[0]; int bi = 0;
    for (int k = 1; k < IN_DIM; ++k) { float v = row[k]; if (v > best) { best = v; bi = k; } }
    sel_s[tid] = bi;
    out_tail[2 + tid] = (float)bi;      // selected_idx as float
  }
  if (tid == 0) out_tail[1] = fmaxf(0.01f, temp[0] * 0.999f);  // new_temp

  // load A_tilde into buf[0] (padded)
  for (int i = tid; i < L * L; i += 256)
    buf[0][(i >> 6) * LDSTRIDE + (i & 63)] = A_tilde[i];
  __syncthreads();

  // scatter phi: M[l][clip(sel[p])] += phi_bar_t[p][l]; rows owned per-thread (no races)
  if (tid < L) {
    for (int p = 0; p < P; ++p) {
      int kk = sel_s[p]; if (kk > L - 1) kk = L - 1;
      buf[0][tid * LDSTRIDE + kk] += phi_bar_t[p * L + tid];
    }
  }
  // xh0 reduce (different threads, no conflict with scatter)
  if (tid >= 64 && tid < 128) {
    int l = tid - 64; float s = 0.f;
    for (int b = 0; b < 64; ++b) s += part[b * 64 + l];
    xh0[l] = s;
  }
  __syncthreads();

  // write W_0 = M to global
  for (int i = tid; i < L * L; i += 256)
    Wm[i] = buf[0][(i >> 6) * LDSTRIDE + (i & 63)];

  // 12 sequential squarings: W_j = W_{j-1}^2
  int r = tid & 63, cg = tid >> 6;
  int c0 = cg * 16;
  int cur = 0;
  for (int j = 1; j <= 12; ++j) {
    const float* S = buf[cur];
    float* D = buf[cur ^ 1];
    float ar[64];
    #pragma unroll
    for (int k = 0; k < 64; ++k) ar[k] = S[r * LDSTRIDE + k];   // 2-way bank = free
    float acc[16];
    #pragma unroll
    for (int c = 0; c < 16; ++c) acc[c] = 0.f;
    #pragma unroll 4
    for (int k = 0; k < 64; ++k) {
      const float2* bp = (const float2*)(S + k * LDSTRIDE + c0); // broadcast reads
      #pragma unroll
      for (int c2 = 0; c2 < 8; ++c2) {
        float2 b2 = bp[c2];
        acc[2 * c2]     += ar[k] * b2.x;
        acc[2 * c2 + 1] += ar[k] * b2.y;
      }
    }
    #pragma unroll
    for (int c = 0; c < 16; ++c) D[r * LDSTRIDE + c0 + c] = acc[c];
    float* Wout = Wm + j * 4096;
    #pragma unroll
    for (int c = 0; c < 16; ++c) Wout[r * 64 + c0 + c] = acc[c];
    __syncthreads();
    cur ^= 1;
  }
}

// ---------------- kernel C: states via checkpoints + serial steps, TRANSPOSED out ----------------
// Writes xseqT[l][t] (64 x 8192) so k_xrec can stage k-major tiles without an
// in-kernel transpose. Scattered stores (64 rows per wave-instr) -> L2, 2 MiB total.
__global__ __launch_bounds__(64) void k_states(const float* __restrict__ Wm,
                                               const float* __restrict__ xh0,
                                               float* __restrict__ xseqT) {
  int c = blockIdx.x;       // 512 chunks of 16 steps
  int l = threadIdx.x;      // 64 lanes; lane l owns component l
  float v = xh0[l];
  int e = c << 4;           // starting exponent = 16*c (bits 4..12)
  for (int j = 4; j <= 12; ++j) {
    if ((e >> j) & 1) {
      const float* W = Wm + j * 4096;
      float n0 = 0.f, n1 = 0.f, n2 = 0.f, n3 = 0.f;
      #pragma unroll
      for (int k = 0; k < 64; k += 4) {
        n0 += W[l * 64 + k]     * __shfl(v, k, 64);
        n1 += W[l * 64 + k + 1] * __shfl(v, k + 1, 64);
        n2 += W[l * 64 + k + 2] * __shfl(v, k + 2, 64);
        n3 += W[l * 64 + k + 3] * __shfl(v, k + 3, 64);
      }
      v = (n0 + n1) + (n2 + n3);
    }
  }
  // M row l into registers
  float m[64];
  #pragma unroll
  for (int k = 0; k < 64; ++k) m[k] = Wm[l * 64 + k];
  int t0 = c * S_CHUNK;
  for (int i = 0; i < S_CHUNK; ++i) {
    float n0 = 0.f, n1 = 0.f, n2 = 0.f, n3 = 0.f;
    #pragma unroll
    for (int k = 0; k < 64; k += 4) {
      n0 += m[k]     * __shfl(v, k, 64);
      n1 += m[k + 1] * __shfl(v, k + 1, 64);
      n2 += m[k + 2] * __shfl(v, k + 2, 64);
      n3 += m[k + 3] * __shfl(v, k + 3, 64);
    }
    v = (n0 + n1) + (n2 + n3);
    xseqT[(size_t)l * T_DIM + (t0 + i)] = v;  // xh_seq[t0+i][l] = (M^{t0+i+1} xh0)[l]
  }
}

// ---------------- kernel D: X_rec = xh_seq @ U^T, register-tiled GEMM, fused err ----------------
// 128t x 128n tile, 256 threads, 8x8 micro-tile (statically indexed -> stays in
// VGPRs; round-1/2 lesson: hipcc will NOT keep a 64-elem per-thread array live).
// LDS: xsT[64][128] + usT[64][128] = exactly 64 KiB, k-major, XOR-swizzled at
// float4 granularity (slot = quad ^ (k&7)) -> main-loop reads conflict-free.
__global__ __launch_bounds__(256, 2) void k_xrec(const float* __restrict__ xseqT,
                                                 const float* __restrict__ U,
                                                 const float* __restrict__ Y,
                                                 float* __restrict__ Xrec,
                                                 double* __restrict__ acc_g) {
  __shared__ float xsT[64 * 128];   // [k][t-swizzled]
  __shared__ float usT[64 * 128];   // [k][n-swizzled]

  int tid = threadIdx.x;
  int nt = blockIdx.x & 31;         // 32 n-tiles
  int tt = blockIdx.x >> 5;         // 64 t-tiles
  int n0 = nt * 128;
  int t0 = tt * 128;
  int tx = tid & 15;                // n micro-group
  int ty = tid >> 4;                // t micro-group (0..15)

  // ---- stage xsT from xseqT (k-major rows, coalesced), swizzled write ----
  #pragma unroll
  for (int i = 0; i < 8; ++i) {
    int f = tid + 256 * i;          // 0..2047
    int k = f >> 5, j = f & 31;     // row k, t-quad j
    float4 val = *(const float4*)(xseqT + (size_t)k * T_DIM + t0 + 4 * j);
    *(float4*)(xsT + k * 128 + ((j ^ (k & 7)) << 2)) = val;
  }
  // ---- stage usT from U (transpose: read [n][k] float4, scatter 4 scalars) ----
  #pragma unroll
  for (int i = 0; i < 8; ++i) {
    int f = tid + 256 * i;
    int np = f >> 4, kq = f & 15;   // local n row, k-quad
    float4 val = *(const float4*)(U + (size_t)(n0 + np) * L + 4 * kq);
    int q = np >> 2, r = np & 3;
    usT[(4 * kq + 0) * 128 + ((q ^ ((4 * kq + 0) & 7)) << 2) + r] = val.x;
    usT[(4 * kq + 1) * 128 + ((q ^ ((4 * kq + 1) & 7)) << 2) + r] = val.y;
    usT[(4 * kq + 2) * 128 + ((q ^ ((4 * kq + 2) & 7)) << 2) + r] = val.z;
    usT[(4 * kq + 3) * 128 + ((q ^ ((4 * kq + 3) & 7)) << 2) + r] = val.w;
  }
  __syncthreads();

  // ---- main loop: thread owns t = t0+ty*8+{0..7}, n = n0+tx*4+{0..3} and +64 ----
  float acc[8][8];
  #pragma unroll
  for (int a = 0; a < 8; ++a)
    #pragma unroll
    for (int b = 0; b < 8; ++b) acc[a][b] = 0.f;

  #pragma unroll 8
  for (int k = 0; k < 64; ++k) {
    int v = k & 7;
    float4 xa = *(const float4*)(xsT + k * 128 + (((ty * 2)     ^ v) << 2));
    float4 xb = *(const float4*)(xsT + k * 128 + (((ty * 2 + 1) ^ v) << 2));
    float4 ua = *(const float4*)(usT + k * 128 + ((tx        ^ v) << 2));
    float4 ub = *(const float4*)(usT + k * 128 + (((16 + tx) ^ v) << 2));
    float xr[8] = {xa.x, xa.y, xa.z, xa.w, xb.x, xb.y, xb.z, xb.w};
    float ur[8] = {ua.x, ua.y, ua.z, ua.w, ub.x, ub.y, ub.z, ub.w};
    #pragma unroll
    for (int a = 0; a < 8; ++a)
      #pragma unroll
      for (int b = 0; b < 8; ++b)
        acc[a][b] += xr[a] * ur[b];
  }

  // ---- epilogue: store Xrec, fused err partials ----
  float sd = 0.f, sy = 0.f;
  #pragma unroll
  for (int a = 0; a < 8; ++a) {
    size_t t = (size_t)t0 + ty * 8 + a;
    size_t base = t * N_DIM + n0 + tx * 4;
    float4 ya = *(const float4*)(Y + base);
    float4 yb = *(const float4*)(Y + base + 64);
    float4 va = {acc[a][0], acc[a][1], acc[a][2], acc[a][3]};
    float4 vb = {acc[a][4], acc[a][5], acc[a][6], acc[a][7]};
    float d;
    d = ya.x - va.x; sd += d * d; sy += ya.x * ya.x;
    d = ya.y - va.y; sd += d * d; sy += ya.y * ya.y;
    d = ya.z - va.z; sd += d * d; sy += ya.z * ya.z;
    d = ya.w - va.w; sd += d * d; sy += ya.w * ya.w;
    d = yb.x - vb.x; sd += d * d; sy += yb.x * yb.x;
    d = yb.y - vb.y; sd += d * d; sy += yb.y * yb.y;
    d = yb.z - vb.z; sd += d * d; sy += yb.z * yb.z;
    d = yb.w - vb.w; sd += d * d; sy += yb.w * yb.w;
    *(float4*)(Xrec + base) = va;
    *(float4*)(Xrec + base + 64) = vb;
  }

  // ---- block reduction (reuse xsT space; xsT no longer needed) ----
  __syncthreads();
  float* rs = xsT;
  float* ry = xsT + 256;
  rs[tid] = sd; ry[tid] = sy;
  __syncthreads();
  for (int s = 128; s > 0; s >>= 1) {
    if (tid < s) { rs[tid] += rs[tid + s]; ry[tid] += ry[tid + s]; }
    __syncthreads();
  }
  if (tid == 0) {
    atomicAdd(acc_g,     (double)rs[0]);
    atomicAdd(acc_g + 1, (double)ry[0]);
  }
}

// ---------------- kernel E: finalize err ----------------
__global__ void k_err(const double* __restrict__ acc, float* __restrict__ out_tail) {
  out_tail[0] = (float)sqrt(acc[0] / acc[1]);
}

extern "C" void kernel_launch(void* const* d_in, const int* in_sizes, int n_in,
                              void* d_out, int out_size, void* d_ws, size_t ws_size,
                              hipStream_t stream) {
  const float* X_train = (const float*)d_in[1];   // (T, N), row 0 = x0
  const float* Y       = (const float*)d_in[2];   // (T, N)
  const float* temp    = (const float*)d_in[3];
  const float* phi     = (const float*)d_in[4];   // (P, L)
  const float* A_tilde = (const float*)d_in[5];   // (L, L)
  const float* U       = (const float*)d_in[6];   // (N, L)
  const float* logits  = (const float*)d_in[7];   // (P, IN_DIM)
  float* out = (float*)d_out;
  float* out_tail = out + (size_t)T_DIM * N_DIM;  // [err, new_temp, sel[32]]

  // workspace layout (bytes)
  char* w = (char*)d_ws;
  double* acc  = (double*)w;                       // 2 doubles
  float* Wm    = (float*)(w + 64);                 // 13 * 4096 floats
  float* xh0   = (float*)(w + 64 + 13 * 16384);    // 64 floats
  float* part  = (float*)(w + 213312);             // 64*64 floats
  float* xseqT = (float*)(w + 262144);             // 64 x 8192 floats (2 MiB), transposed

  hipMemsetAsync(acc, 0, 2 * sizeof(double), stream);

  k_xh0_part<<<64, 64, 0, stream>>>(U, X_train, part);
  k_prep<<<1, 256, 0, stream>>>(A_tilde, phi, logits, temp, part, Wm, xh0, out_tail);
  k_states<<<N_CHUNK, 64, 0, stream>>>(Wm, xh0, xseqT);
  k_xrec<<<2048, 256, 0, stream>>>(xseqT, U, Y, out, acc);
  k_err<<<1, 1, 0, stream>>>(acc, out_tail);
}